// Round 6
// baseline (194.376 us; speedup 1.0000x reference)
//
#include <hip/hip_runtime.h>
#include <hip/hip_bf16.h>

// TriangleAttentionStartingNode  B=1, N=256, C_Z=128, H=4, D=32, TOTAL=128
// Round 6: mega-fusion. 3 kernels:
//   prep:  pack W^T (Q pre-scaled) + Wo^T into MFMA-frag-order bf16 (tiny)
//   bias:  LN + x@Wb in fp32 -> BbF (1 MB) scattered in attn-frag order
//   fused: one block per i (256 x 1024thr): LN->frags in reg; per-head K/V
//          proj into frag-order LDS; Q/P via in-register shfl transpose;
//          bias preloaded into MFMA acc; attention; gvals through aliased
//          LDS; fused oproj -> out. No intermediate HBM traffic.

#define QSCALE 0.17677669529663687f  // 1/sqrt(32)

typedef __attribute__((ext_vector_type(8))) short bf16x8;
typedef __attribute__((ext_vector_type(4))) float f32x4;

__device__ __forceinline__ ushort f2bf(float f) {
    uint32_t u = __builtin_bit_cast(uint32_t, f);
    uint32_t r = (u + 0x7FFFu + ((u >> 16) & 1u)) >> 16;  // RNE
    return (ushort)r;
}
__device__ __forceinline__ uint pk2(float a, float b) {   // v_cvt_pk_bf16_f32
    union { __hip_bfloat162 h; uint u; } cv;
    cv.h = __float22bfloat162_rn(make_float2(a, b));
    return cv.u;
}
__device__ __forceinline__ float4 ld4f(const float* p) { return *(const float4*)p; }

// C-layout (16x16 tile pair, rows = transpose-target k/d dim) -> B/A-frag.
// A = tile covering rows 0..15 (packed: .x = pk2(r0,r1), .y = pk2(r2,r3)),
// B = rows 16..31. Output: lane quad*16+m holds elems e: row = quad*8+e.
__device__ __forceinline__ bf16x8 xpose(uint2 A, uint2 B, int quad, int m) {
    int s0 = ((quad & 1) << 5) + m;   // ((quad&1)*2)*16 + m
    int s1 = s0 + 16;
    uint a0 = (uint)__shfl((int)A.x, s0), a1 = (uint)__shfl((int)A.y, s0);
    uint a2 = (uint)__shfl((int)A.x, s1), a3 = (uint)__shfl((int)A.y, s1);
    uint b0 = (uint)__shfl((int)B.x, s0), b1 = (uint)__shfl((int)B.y, s0);
    uint b2 = (uint)__shfl((int)B.x, s1), b3 = (uint)__shfl((int)B.y, s1);
    bool lo = quad < 2;
    union { bf16x8 v; uint u[4]; } r;
    r.u[0] = lo ? a0 : b0;
    r.u[1] = lo ? a1 : b1;
    r.u[2] = lo ? a2 : b2;
    r.u[3] = lo ? a3 : b3;
    return r.v;
}

// ---------------------------------------------------------------------------
// prep: Wfrag[ct 0..31][ks][lane][e]: n = ct*16+(lane&15), k = ks*32+(lane>>4)*8+e
//   n: 0..127 Wq*QSCALE, 128..255 Wk, 256..383 Wv, 384..511 Wg.
// WoFrag: 8 ct over Wo^T.  grid 320*256 = 65536 + 16384.
// ---------------------------------------------------------------------------
__global__ __launch_bounds__(256) void prep_kernel(
    const float* __restrict__ Wq, const float* __restrict__ Wk, const float* __restrict__ Wv,
    const float* __restrict__ Wg, const float* __restrict__ Wo,
    ushort* __restrict__ Wfrag, ushort* __restrict__ WoFrag)
{
    int idx = blockIdx.x * 256 + threadIdx.x;
    if (idx < 65536) {
        int e = idx & 7, lane = (idx >> 3) & 63, ks = (idx >> 9) & 3, ct = idx >> 11;
        int n = ct * 16 + (lane & 15);
        int k = ks * 32 + (lane >> 4) * 8 + e;
        float v;
        if (n < 128)      v = Wq[k * 128 + n] * QSCALE;
        else if (n < 256) v = Wk[k * 128 + (n - 128)];
        else if (n < 384) v = Wv[k * 128 + (n - 256)];
        else              v = Wg[k * 128 + (n - 384)];
        Wfrag[idx] = f2bf(v);
    } else {
        int idx2 = idx - 65536;
        int e = idx2 & 7, lane = (idx2 >> 3) & 63, ks = (idx2 >> 9) & 3, ct = idx2 >> 11;
        int n = ct * 16 + (lane & 15);
        int k = ks * 32 + (lane >> 4) * 8 + e;
        WoFrag[idx2] = f2bf(Wo[k * 128 + n]);
    }
}

// ---------------------------------------------------------------------------
// bias: per x-row p=(j,k): LN in fp32, dot with Wb -> 4 fp32, scatter into
// BbF[h*65536 + (j>>4)*4096 + (k>>4)*256 + ((k&15)>>2)*64 + (j&15)*4 + (k&3)].
// 512 blocks x 256 thr, 2 threads/row.
// ---------------------------------------------------------------------------
__global__ __launch_bounds__(256) void bias_kernel(
    const float* __restrict__ x, const float* __restrict__ gamma,
    const float* __restrict__ beta, const float* __restrict__ Wb,
    float* __restrict__ BbF)
{
    const int t = threadIdx.x;
    const int p = blockIdx.x * 128 + (t >> 1);
    const int half = t & 1;
    const float* rp = x + p * 128 + half * 64;
    float4 v[16];
    float sum = 0.f, ssq = 0.f;
#pragma unroll
    for (int ii = 0; ii < 16; ++ii) {
        v[ii] = ld4f(rp + ii * 4);
        sum += v[ii].x + v[ii].y + v[ii].z + v[ii].w;
        ssq += v[ii].x * v[ii].x + v[ii].y * v[ii].y + v[ii].z * v[ii].z + v[ii].w * v[ii].w;
    }
    sum += __shfl_xor(sum, 1);
    ssq += __shfl_xor(ssq, 1);
    float mu = sum * (1.f / 128.f);
    float var = ssq * (1.f / 128.f) - mu * mu;
    float rstd = rsqrtf(var + 1e-5f);

    float d0 = 0.f, d1 = 0.f, d2 = 0.f, d3 = 0.f;
#pragma unroll
    for (int ii = 0; ii < 16; ++ii) {
        int c = half * 64 + ii * 4;
        float4 g4 = ld4f(gamma + c), b4 = ld4f(beta + c);
        float n0 = (v[ii].x - mu) * rstd * g4.x + b4.x;
        float n1 = (v[ii].y - mu) * rstd * g4.y + b4.y;
        float n2 = (v[ii].z - mu) * rstd * g4.z + b4.z;
        float n3 = (v[ii].w - mu) * rstd * g4.w + b4.w;
        float4 w0 = ld4f(Wb + (c + 0) * 4);
        float4 w1 = ld4f(Wb + (c + 1) * 4);
        float4 w2 = ld4f(Wb + (c + 2) * 4);
        float4 w3 = ld4f(Wb + (c + 3) * 4);
        d0 += n0 * w0.x + n1 * w1.x + n2 * w2.x + n3 * w3.x;
        d1 += n0 * w0.y + n1 * w1.y + n2 * w2.y + n3 * w3.y;
        d2 += n0 * w0.z + n1 * w1.z + n2 * w2.z + n3 * w3.z;
        d3 += n0 * w0.w + n1 * w1.w + n2 * w2.w + n3 * w3.w;
    }
    d0 += __shfl_xor(d0, 1);
    d1 += __shfl_xor(d1, 1);
    d2 += __shfl_xor(d2, 1);
    d3 += __shfl_xor(d3, 1);
    if (half == 0) {
        int j = p >> 8, k = p & 255;
        int base = ((j >> 4) * 16 + (k >> 4)) * 256 + ((k & 15) >> 2) * 64 + (j & 15) * 4 + (k & 3);
        BbF[base]          = d0;
        BbF[base + 65536]  = d1;
        BbF[base + 131072] = d2;
        BbF[base + 196608] = d3;
    }
}

// ---------------------------------------------------------------------------
// fused: grid 256 (i), 1024 thr = 16 waves; wave w owns rows/queries
// j = w*16 + (lane&15). LN -> xnf frags in registers. Loop h: project K/V
// (frag-order LDS), Q/G (registers); barrier; flash attention with bias in
// acc and shfl-transposed P; barrier. Then gvals -> aliased LDS, oproj.
// ---------------------------------------------------------------------------
__global__ __launch_bounds__(1024) void fused_kernel(
    const float* __restrict__ x, const float* __restrict__ gamma,
    const float* __restrict__ beta, const ushort* __restrict__ Wfrag,
    const float* __restrict__ bg, const float* __restrict__ BbF,
    const ushort* __restrict__ WoFrag, const float* __restrict__ bo,
    float* __restrict__ out)
{
    __shared__ ushort smem[32768];       // 64 KB
    ushort* K_s = smem;                  // [16 kk][64 lane][8]  = 8192 elems
    ushort* V_s = smem + 8192;           // [8 kc][2 dt][64][8]  = 8192 elems
    ushort* GV_s = smem;                 // 32768 elems (aliases K/V after barrier)

    const int t = threadIdx.x;
    const int w = t >> 6, lane = t & 63, m = lane & 15, quad = lane >> 4;
    const int i = blockIdx.x;

    // ---- LN -> bf16 frags (lane&15 = row w*16+m, elems = ks*32+quad*8+e) ----
    const float* xr = x + (i * 256 + w * 16 + m) * 128 + quad * 8;
    float4 xa[4][2];
    float sum = 0.f, ssq = 0.f;
#pragma unroll
    for (int ks = 0; ks < 4; ++ks) {
        xa[ks][0] = ld4f(xr + ks * 32);
        xa[ks][1] = ld4f(xr + ks * 32 + 4);
#pragma unroll
        for (int q4 = 0; q4 < 2; ++q4) {
            float4 vv = xa[ks][q4];
            sum += vv.x + vv.y + vv.z + vv.w;
            ssq += vv.x * vv.x + vv.y * vv.y + vv.z * vv.z + vv.w * vv.w;
        }
    }
    sum += __shfl_xor(sum, 16); ssq += __shfl_xor(ssq, 16);
    sum += __shfl_xor(sum, 32); ssq += __shfl_xor(ssq, 32);
    const float mu = sum * (1.f / 128.f);
    const float var = ssq * (1.f / 128.f) - mu * mu;
    const float rstd = rsqrtf(var + 1e-5f);

    bf16x8 xnf[4];
#pragma unroll
    for (int ks = 0; ks < 4; ++ks) {
        const int c = ks * 32 + quad * 8;
        float4 g0 = ld4f(gamma + c), g1 = ld4f(gamma + c + 4);
        float4 b0 = ld4f(beta + c),  b1 = ld4f(beta + c + 4);
        float4 v0 = xa[ks][0], v1 = xa[ks][1];
        union { bf16x8 v; uint u[4]; } xu;
        xu.u[0] = pk2((v0.x - mu) * rstd * g0.x + b0.x, (v0.y - mu) * rstd * g0.y + b0.y);
        xu.u[1] = pk2((v0.z - mu) * rstd * g0.z + b0.z, (v0.w - mu) * rstd * g0.w + b0.w);
        xu.u[2] = pk2((v1.x - mu) * rstd * g1.x + b1.x, (v1.y - mu) * rstd * g1.y + b1.y);
        xu.u[3] = pk2((v1.z - mu) * rstd * g1.z + b1.z, (v1.w - mu) * rstd * g1.w + b1.w);
        xnf[ks] = xu.v;
    }

    uint gst[4][4];   // gvals stash per head (bf16-packed), fully unrolled

#pragma unroll
    for (int h = 0; h < 4; ++h) {
        // ---- K_h: D[ncol=d][p=k] = mfma(wf, xnf) -> frag-order K_s ----
#pragma unroll
        for (int dt = 0; dt < 2; ++dt) {
            const int ct = 8 + 2 * h + dt;
            f32x4 acc = (f32x4){0.f, 0.f, 0.f, 0.f};
#pragma unroll
            for (int ks = 0; ks < 4; ++ks) {
                bf16x8 wf = *(const bf16x8*)(Wfrag + ((ct * 4 + ks) * 64 + lane) * 8);
                acc = __builtin_amdgcn_mfma_f32_16x16x32_bf16(wf, xnf[ks], acc, 0, 0, 0);
            }
            uint2 u; u.x = pk2(acc[0], acc[1]); u.y = pk2(acc[2], acc[3]);
            *(uint2*)(K_s + (w * 64 + (dt * 2 + (quad >> 1)) * 16 + m) * 8 + (quad & 1) * 4) = u;
        }
        // ---- V_h: D[p=k][ncol=d] = mfma(xnf, wf) -> frag-order V_s ----
#pragma unroll
        for (int dt = 0; dt < 2; ++dt) {
            const int ct = 16 + 2 * h + dt;
            f32x4 acc = (f32x4){0.f, 0.f, 0.f, 0.f};
#pragma unroll
            for (int ks = 0; ks < 4; ++ks) {
                bf16x8 wf = *(const bf16x8*)(Wfrag + ((ct * 4 + ks) * 64 + lane) * 8);
                acc = __builtin_amdgcn_mfma_f32_16x16x32_bf16(xnf[ks], wf, acc, 0, 0, 0);
            }
            uint2 u; u.x = pk2(acc[0], acc[1]); u.y = pk2(acc[2], acc[3]);
            *(uint2*)(V_s + (((w >> 1) * 2 + dt) * 512 +
                             (((w & 1) * 2 + (quad >> 1)) * 16 + m) * 8 + (quad & 1) * 4)) = u;
        }
        // ---- Q_h (own 16 j): C-layout -> B-frag via shfl transpose ----
        uint2 qpk[2];
#pragma unroll
        for (int dt = 0; dt < 2; ++dt) {
            const int ct = 2 * h + dt;
            f32x4 acc = (f32x4){0.f, 0.f, 0.f, 0.f};
#pragma unroll
            for (int ks = 0; ks < 4; ++ks) {
                bf16x8 wf = *(const bf16x8*)(Wfrag + ((ct * 4 + ks) * 64 + lane) * 8);
                acc = __builtin_amdgcn_mfma_f32_16x16x32_bf16(wf, xnf[ks], acc, 0, 0, 0);
            }
            qpk[dt].x = pk2(acc[0], acc[1]); qpk[dt].y = pk2(acc[2], acc[3]);
        }
        bf16x8 qf = xpose(qpk[0], qpk[1], quad, m);
        // ---- G_h (own 16 j): sigmoid, kept in C-layout regs (matches O) ----
        f32x4 Gs[2];
#pragma unroll
        for (int dt = 0; dt < 2; ++dt) {
            const int ct = 24 + 2 * h + dt;
            f32x4 acc = (f32x4){0.f, 0.f, 0.f, 0.f};
#pragma unroll
            for (int ks = 0; ks < 4; ++ks) {
                bf16x8 wf = *(const bf16x8*)(Wfrag + ((ct * 4 + ks) * 64 + lane) * 8);
                acc = __builtin_amdgcn_mfma_f32_16x16x32_bf16(wf, xnf[ks], acc, 0, 0, 0);
            }
            float4 bg4 = ld4f(bg + h * 32 + dt * 16 + quad * 4);
            Gs[dt][0] = 1.f / (1.f + __expf(-(acc[0] + bg4.x)));
            Gs[dt][1] = 1.f / (1.f + __expf(-(acc[1] + bg4.y)));
            Gs[dt][2] = 1.f / (1.f + __expf(-(acc[2] + bg4.z)));
            Gs[dt][3] = 1.f / (1.f + __expf(-(acc[3] + bg4.w)));
        }

        __syncthreads();   // K/V visible to all waves

        // ---- attention: 16 queries x 256 keys, bias in acc ----
        f32x4 O0 = (f32x4){0.f, 0.f, 0.f, 0.f};
        f32x4 O1 = (f32x4){0.f, 0.f, 0.f, 0.f};
        float lsum = 0.f;
        const float* bb = BbF + ((h * 16 + w) * 16) * 256 + lane * 4;
#pragma unroll
        for (int kt2 = 0; kt2 < 4; ++kt2) {
            uint2 spk[4];
#pragma unroll
            for (int kk = 0; kk < 4; ++kk) {
                const int tile = kt2 * 4 + kk;
                bf16x8 kf = *(const bf16x8*)(K_s + (tile * 64 + lane) * 8);
                f32x4 bias = *(const f32x4*)(bb + tile * 256);
                f32x4 S = __builtin_amdgcn_mfma_f32_16x16x32_bf16(kf, qf, bias, 0, 0, 0);
                float p0 = __expf(S[0]), p1 = __expf(S[1]);
                float p2 = __expf(S[2]), p3 = __expf(S[3]);
                lsum += p0 + p1 + p2 + p3;
                spk[kk].x = pk2(p0, p1); spk[kk].y = pk2(p2, p3);
            }
#pragma unroll
            for (int kc = 0; kc < 2; ++kc) {
                bf16x8 pf = xpose(spk[kc * 2], spk[kc * 2 + 1], quad, m);
                const int kcg = kt2 * 2 + kc;
                bf16x8 vf0 = *(const bf16x8*)(V_s + ((kcg * 2 + 0) * 512 + lane * 8));
                bf16x8 vf1 = *(const bf16x8*)(V_s + ((kcg * 2 + 1) * 512 + lane * 8));
                O0 = __builtin_amdgcn_mfma_f32_16x16x32_bf16(vf0, pf, O0, 0, 0, 0);
                O1 = __builtin_amdgcn_mfma_f32_16x16x32_bf16(vf1, pf, O1, 0, 0, 0);
            }
        }
        lsum += __shfl_xor(lsum, 16);
        lsum += __shfl_xor(lsum, 32);
        const float rl = 1.f / lsum;
        gst[h][0] = pk2(O0[0] * rl * Gs[0][0], O0[1] * rl * Gs[0][1]);
        gst[h][1] = pk2(O0[2] * rl * Gs[0][2], O0[3] * rl * Gs[0][3]);
        gst[h][2] = pk2(O1[0] * rl * Gs[1][0], O1[1] * rl * Gs[1][1]);
        gst[h][3] = pk2(O1[2] * rl * Gs[1][2], O1[3] * rl * Gs[1][3]);

        __syncthreads();   // all K/V reads done before next h (or GV) overwrites
    }

    // ---- gvals (C-layout [hd][j]) -> frag-order GV_s ----
#pragma unroll
    for (int h = 0; h < 4; ++h) {
#pragma unroll
        for (int dt = 0; dt < 2; ++dt) {
            uint2 u; u.x = gst[h][dt * 2]; u.y = gst[h][dt * 2 + 1];
            *(uint2*)(GV_s + ((w * 4 + h) * 512 +
                              ((dt * 2 + (quad >> 1)) * 16 + m) * 8 + (quad & 1) * 4)) = u;
        }
    }
    __syncthreads();

    // ---- oproj: D[p=j][n=c] = mfma(gf, wf) + bo -> out ----
#pragma unroll
    for (int ct = 0; ct < 8; ++ct) {
        f32x4 acc = (f32x4){0.f, 0.f, 0.f, 0.f};
#pragma unroll
        for (int ks = 0; ks < 4; ++ks) {
            bf16x8 wf = *(const bf16x8*)(WoFrag + ((ct * 4 + ks) * 64 + lane) * 8);
            bf16x8 gf = *(const bf16x8*)(GV_s + ((w * 4 + ks) * 512 + lane * 8));
            acc = __builtin_amdgcn_mfma_f32_16x16x32_bf16(gf, wf, acc, 0, 0, 0);
        }
        const float bov = bo[ct * 16 + m];
#pragma unroll
        for (int r = 0; r < 4; ++r)
            out[(i * 256 + w * 16 + quad * 4 + r) * 128 + ct * 16 + m] = acc[r] + bov;
    }
}

// ---------------------------------------------------------------------------
extern "C" void kernel_launch(void* const* d_in, const int* in_sizes, int n_in,
                              void* d_out, int out_size, void* d_ws, size_t ws_size,
                              hipStream_t stream) {
    const float* x     = (const float*)d_in[0];
    const float* gamma = (const float*)d_in[1];
    const float* beta  = (const float*)d_in[2];
    const float* Wq    = (const float*)d_in[3];
    const float* Wk    = (const float*)d_in[4];
    const float* Wv    = (const float*)d_in[5];
    const float* Wb    = (const float*)d_in[6];
    const float* Wg    = (const float*)d_in[7];
    const float* bg    = (const float*)d_in[8];
    const float* Wo    = (const float*)d_in[9];
    const float* bo    = (const float*)d_in[10];

    ushort* Wfrag  = (ushort*)d_ws;            // 65536 elems
    ushort* WoFrag = Wfrag + 65536;            // 16384 elems
    float*  BbF    = (float*)(WoFrag + 16384); // 262144 fp32 (1 MB)
    // total ~1.2 MB of d_ws

    prep_kernel<<<320, 256, 0, stream>>>(Wq, Wk, Wv, Wg, Wo, Wfrag, WoFrag);
    bias_kernel<<<512, 256, 0, stream>>>(x, gamma, beta, Wb, BbF);
    fused_kernel<<<256, 1024, 0, stream>>>(x, gamma, beta, Wfrag, bg, BbF,
                                           WoFrag, bo, (float*)d_out);
}